// Round 1
// baseline (576.944 us; speedup 1.0000x reference)
//
#include <hip/hip_runtime.h>

typedef __attribute__((ext_vector_type(8))) short short8;
typedef __attribute__((ext_vector_type(4))) float f32x4;

constexpr int L = 1024, C = 256, F = 256;
constexpr int NIMG = 256;          // B*M
constexpr int LOUT = 1022;         // L - K + 1
constexpr int KTOT = 768;          // K*C
constexpr int BK = 32;
constexpr int NKI = KTOT / BK;     // 24
constexpr int LDT = 40;            // padded k-stride (bf16 elems): 80B = 20 banks -> 2-way max on b128 reads
constexpr long MAXROW = (long)NIMG * L - 1;

__device__ inline unsigned short f2bf(float f) {
  union { float f; unsigned u; } v; v.f = f;
  return (unsigned short)((v.u + 0x7FFFu + ((v.u >> 16) & 1u)) >> 16);  // RNE; data has no NaN/inf
}

__device__ inline void g2l16(const unsigned short* g, unsigned short* l) {
  __builtin_amdgcn_global_load_lds(
      (const __attribute__((address_space(1))) unsigned int*)g,
      (__attribute__((address_space(3))) unsigned int*)l, 16, 0, 0);
}

// Pre-pass: W (768x256 fp32, row-major kc x f) -> Wt bf16, layout [kk][fh][n'][k' pad 40]
// so each main-kernel B tile (128 x 40 bf16 = 10240 B) is one contiguous chunk.
__global__ void wprep(const float* __restrict__ W, unsigned short* __restrict__ Wt) {
  int tid = blockIdx.x * 256 + threadIdx.x;
  if (tid >= KTOT * F) return;
  int kc = tid >> 8, f = tid & 255;            // coalesced read of W[tid]
  int kk = kc >> 5, kp = kc & 31;
  int fh = f >> 7,  np = f & 127;
  Wt[((size_t)(kk * 2 + fh) * 128 + np) * LDT + kp] = f2bf(W[tid]);
}

__global__ __launch_bounds__(256) void conv_mfma(
    const float* __restrict__ x, const unsigned short* __restrict__ Wt,
    const float* __restrict__ bias, float* __restrict__ y)
{
  __shared__ __align__(16) unsigned short As[128 * LDT];  // 10240 B
  __shared__ __align__(16) unsigned short Bs[128 * LDT];  // 10240 B

  const int bid = blockIdx.x;
  const int fh  = bid & 1;          // F half (0/1): paired blocks share the x tile -> L3 hit
  const int mt  = (bid >> 1) & 7;   // 8 m-tiles of 128 rows over Lout=1022
  const int img = bid >> 4;         // 256 images
  const int l0  = mt * 128;

  const int tid  = threadIdx.x;
  const int lane = tid & 63;
  const int wv   = tid >> 6;        // 4 waves: 2x2 grid of 64x64 sub-tiles
  const int wr   = wv >> 1;
  const int wc   = wv & 1;
  const int lr   = lane & 15;
  const int quad = lane >> 4;

  const int rbase = tid >> 3;       // A staging: thread covers rows rbase + 32j
  const int c8    = tid & 7;        // ... at float4 column c8

  f32x4 acc[4][4] = {};
  float4 av[4];

  auto load_A = [&](int kk) {       // A tile for iter kk: x[img][l0+k+row][c0 .. c0+32)
    const int k  = kk >> 3;
    const int c0 = (kk & 7) << 5;
    const long growb = (long)img * L + l0 + k + rbase;
#pragma unroll
    for (int j = 0; j < 4; ++j) {
      long gr = growb + j * 32;
      if (gr > MAXROW) gr = MAXROW;              // clamp OOB tail rows (only feed masked outputs)
      av[j] = *(const float4*)(x + gr * C + c0 + (c8 << 2));
    }
  };

  load_A(0);

  for (int kk = 0; kk < NKI; ++kk) {
    __syncthreads();                              // prev iter's frag reads done
    // A: convert fp32 regs -> bf16, write LDS (pad-40 stride, <=2-way bank aliasing)
#pragma unroll
    for (int j = 0; j < 4; ++j) {
      const int row = rbase + j * 32;
      ushort4 w4;
      w4.x = f2bf(av[j].x); w4.y = f2bf(av[j].y);
      w4.z = f2bf(av[j].z); w4.w = f2bf(av[j].w);
      *(ushort4*)(As + row * LDT + (c8 << 2)) = w4;
    }
    // B: contiguous 10240 B = 640 x 16B chunks, direct global->LDS (lane-order layout holds)
    {
      const unsigned short* bsrc = Wt + (size_t)(kk * 2 + fh) * 128 * LDT;
      g2l16(bsrc + (size_t)tid * 8,         Bs + (size_t)tid * 8);
      g2l16(bsrc + (size_t)(tid + 256) * 8, Bs + (size_t)(tid + 256) * 8);
      if (tid < 128)                              // waves 0,1 only (wave-uniform)
        g2l16(bsrc + (size_t)(tid + 512) * 8, Bs + (size_t)(tid + 512) * 8);
    }
    __syncthreads();                              // vmcnt(0) drain: staging visible

    if (kk + 1 < NKI) load_A(kk + 1);             // prefetch next A during MFMA phase

    short8 af[4], bf[4];
#pragma unroll
    for (int mi = 0; mi < 4; ++mi) {              // A[m=lr][k=quad*8+j]
      const int row = wr * 64 + mi * 16 + lr;
      af[mi] = *(const short8*)(As + row * LDT + quad * 8);
    }
#pragma unroll
    for (int ni = 0; ni < 4; ++ni) {              // B[k=quad*8+j][n=lr], Bs stored [n][k']
      const int nr = wc * 64 + ni * 16 + lr;
      bf[ni] = *(const short8*)(Bs + nr * LDT + quad * 8);
    }
#pragma unroll
    for (int mi = 0; mi < 4; ++mi)
#pragma unroll
      for (int ni = 0; ni < 4; ++ni)
        acc[mi][ni] = __builtin_amdgcn_mfma_f32_16x16x32_bf16(af[mi], bf[ni], acc[mi][ni], 0, 0, 0);
  }

  // Epilogue: C/D layout col=lane&15, row=quad*4+reg (m89/m91-verified)
  float bv[4];
#pragma unroll
  for (int ni = 0; ni < 4; ++ni)
    bv[ni] = bias[fh * 128 + wc * 64 + ni * 16 + lr];

#pragma unroll
  for (int mi = 0; mi < 4; ++mi) {
#pragma unroll
    for (int r = 0; r < 4; ++r) {
      const int lrow = l0 + wr * 64 + mi * 16 + quad * 4 + r;
      if (lrow < LOUT) {
        float* yp = y + ((size_t)img * LOUT + lrow) * F + fh * 128 + wc * 64 + lr;
#pragma unroll
        for (int ni = 0; ni < 4; ++ni)
          yp[ni * 16] = acc[mi][ni][r] + bv[ni];
      }
    }
  }
}

extern "C" void kernel_launch(void* const* d_in, const int* in_sizes, int n_in,
                              void* d_out, int out_size, void* d_ws, size_t ws_size,
                              hipStream_t stream) {
  const float* x = (const float*)d_in[0];   // (8,32,1024,256) fp32
  const float* W = (const float*)d_in[1];   // (3,256,256) fp32 == (768,256) row-major
  const float* b = (const float*)d_in[2];   // (256,) fp32
  float* y = (float*)d_out;                 // (8,32,1022,256) fp32
  unsigned short* Wt = (unsigned short*)d_ws;  // 24*2*128*40*2 B = 491,520 B

  wprep<<<(KTOT * F + 255) / 256, 256, 0, stream>>>(W, Wt);
  conv_mfma<<<NIMG * 8 * 2, 256, 0, stream>>>(x, Wt, b, y);
}

// Round 2
// 523.673 us; speedup vs baseline: 1.1017x; 1.1017x over previous
//
#include <hip/hip_runtime.h>

typedef __attribute__((ext_vector_type(8))) short short8;
typedef __attribute__((ext_vector_type(4))) float f32x4;

constexpr int L = 1024, C = 256, F = 256;
constexpr int NIMG = 256;          // B*M
constexpr int LOUT = 1022;         // L - K + 1
constexpr long MAXROW = (long)NIMG * L - 1;

__device__ inline unsigned short f2bf(float f) {
  union { float f; unsigned u; } v; v.f = f;
  return (unsigned short)((v.u + 0x7FFFu + ((v.u >> 16) & 1u)) >> 16);  // RNE
}

__device__ inline void g2l16(const unsigned short* g, unsigned short* l) {
  __builtin_amdgcn_global_load_lds(
      (const __attribute__((address_space(1))) unsigned int*)g,
      (__attribute__((address_space(3))) unsigned int*)l, 16, 0, 0);
}

// Pre-pass: W (3,256,256) fp32 -> Wt bf16, layout [slab(8)][k(3)][fh(2)][f'(128)][kp(32)]
// so each main-kernel B tile (128x32 bf16 = 8 KB) is one contiguous chunk in LDS order.
__global__ void wprep(const float* __restrict__ W, unsigned short* __restrict__ Wt) {
  int tid = blockIdx.x * 256 + threadIdx.x;       // exactly 768*256 threads
  int kc = tid >> 8, f = tid & 255;               // coalesced read of W[tid]
  int k = kc >> 8, c = kc & 255;
  int slab = c >> 5, kp = c & 31;
  int fh = f >> 7, fp = f & 127;
  Wt[(size_t)((((slab * 3 + k) * 2 + fh) * 128 + fp) * 32 + kp)] = f2bf(W[tid]);
}

__global__ __launch_bounds__(256) void conv_mfma(
    const float* __restrict__ x, const unsigned short* __restrict__ Wt,
    const float* __restrict__ bias, float* __restrict__ y)
{
  // Unpadded 64 B (32 bf16) row stride: whole-wave b128 tile accesses cover a
  // contiguous region -> every bank hit equally (balanced) -> no conflict penalty.
  __shared__ __align__(16) unsigned short As[130 * 32];  // 8320 B, rows l0..l0+129
  __shared__ __align__(16) unsigned short Bs[128 * 32];  // 8192 B

  const int bid = blockIdx.x;
  const int fh  = bid & 1;          // F half; paired blocks share the x tile -> L3 hit
  const int mt  = (bid >> 1) & 7;   // 8 m-tiles of 128 rows over Lout=1022
  const int img = bid >> 4;         // 256 images
  const int l0  = mt * 128;

  const int tid  = threadIdx.x;
  const int lane = tid & 63;
  const int wv   = tid >> 6;        // 4 waves: 2x2 grid of 64x64 sub-tiles
  const int wr   = wv >> 1;
  const int wc   = wv & 1;
  const int lr   = lane & 15;
  const int quad = lane >> 4;

  f32x4 acc[4][4] = {};
  float4 av[2][2];                  // A prefetch regs: chunks tid, tid+256 (8 floats each)
  float4 avt[2];                    // tail chunks 512..519 (tid < 8)

  const long gb  = (long)img * L + l0;
  const int  qr  = tid >> 2;        // chunk row (chunk = 16 B bf16 = 8 elems)
  const int  qc8 = (tid & 3) * 8;   // chunk col offset in floats

  auto issue_A = [&](int slab) {    // A tile rows 0..129 of x[img][l0+r][slab*32..+32)
    const int cb = slab * 32;
    long g0 = gb + qr;        if (g0 > MAXROW) g0 = MAXROW;   // clamped rows feed only
    long g1 = gb + qr + 64;   if (g1 > MAXROW) g1 = MAXROW;   // masked outputs
    const float* p0 = x + g0 * C + cb + qc8;
    const float* p1 = x + g1 * C + cb + qc8;
    av[0][0] = *(const float4*)p0; av[0][1] = *(const float4*)(p0 + 4);
    av[1][0] = *(const float4*)p1; av[1][1] = *(const float4*)(p1 + 4);
    if (tid < 8) {
      long g2 = gb + 128 + (tid >> 2); if (g2 > MAXROW) g2 = MAXROW;
      const float* p2 = x + g2 * C + cb + (tid & 3) * 8;
      avt[0] = *(const float4*)p2; avt[1] = *(const float4*)(p2 + 4);
    }
  };

  auto pack8 = [&](float4 a, float4 b) {
    short8 r;
    r[0] = (short)f2bf(a.x); r[1] = (short)f2bf(a.y);
    r[2] = (short)f2bf(a.z); r[3] = (short)f2bf(a.w);
    r[4] = (short)f2bf(b.x); r[5] = (short)f2bf(b.y);
    r[6] = (short)f2bf(b.z); r[7] = (short)f2bf(b.w);
    return r;
  };

  auto write_A = [&]() {            // 520 chunks of 16 B; contiguous per wave -> balanced
    *(short8*)(As + (size_t)tid * 8)         = pack8(av[0][0], av[0][1]);
    *(short8*)(As + (size_t)(tid + 256) * 8) = pack8(av[1][0], av[1][1]);
    if (tid < 8)
      *(short8*)(As + (size_t)(512 + tid) * 8) = pack8(avt[0], avt[1]);
  };

  issue_A(0);

  for (int slab = 0; slab < 8; ++slab) {
#pragma unroll
    for (int k = 0; k < 3; ++k) {
      __syncthreads();                            // prev iter's frag reads done
      if (k == 0) write_A();                      // A staged once per slab, reused 3x
      {                                           // B: 8 KB contiguous, direct global->LDS
        const unsigned short* bsrc = Wt + (size_t)((slab * 3 + k) * 2 + fh) * (128 * 32);
        g2l16(bsrc + (size_t)tid * 8,         Bs + (size_t)tid * 8);
        g2l16(bsrc + (size_t)(tid + 256) * 8, Bs + (size_t)(tid + 256) * 8);
      }
      __syncthreads();                            // staging visible

      if (k == 1 && slab < 7) issue_A(slab + 1);  // prefetch next slab's A during MFMA

      short8 af[4], bf[4];
#pragma unroll
      for (int mi = 0; mi < 4; ++mi)              // A[m=lr][kk=quad*8+j], +k row shift
        af[mi] = *(const short8*)(As + (wr * 64 + mi * 16 + lr + k) * 32 + quad * 8);
#pragma unroll
      for (int ni = 0; ni < 4; ++ni)              // B[kk=quad*8+j][n=lr], stored [n][kk]
        bf[ni] = *(const short8*)(Bs + (wc * 64 + ni * 16 + lr) * 32 + quad * 8);
#pragma unroll
      for (int mi = 0; mi < 4; ++mi)
#pragma unroll
        for (int ni = 0; ni < 4; ++ni)
          acc[mi][ni] = __builtin_amdgcn_mfma_f32_16x16x32_bf16(af[mi], bf[ni], acc[mi][ni], 0, 0, 0);
    }
  }

  // Epilogue: C/D layout col=lane&15, row=quad*4+reg (m89/m91-verified)
  float bv[4];
#pragma unroll
  for (int ni = 0; ni < 4; ++ni)
    bv[ni] = bias[fh * 128 + wc * 64 + ni * 16 + lr];

#pragma unroll
  for (int mi = 0; mi < 4; ++mi) {
#pragma unroll
    for (int r = 0; r < 4; ++r) {
      const int lrow = l0 + wr * 64 + mi * 16 + quad * 4 + r;
      if (lrow < LOUT) {
        float* yp = y + ((size_t)img * LOUT + lrow) * F + fh * 128 + wc * 64 + lr;
#pragma unroll
        for (int ni = 0; ni < 4; ++ni)
          yp[ni * 16] = acc[mi][ni][r] + bv[ni];
      }
    }
  }
}

extern "C" void kernel_launch(void* const* d_in, const int* in_sizes, int n_in,
                              void* d_out, int out_size, void* d_ws, size_t ws_size,
                              hipStream_t stream) {
  const float* x = (const float*)d_in[0];   // (8,32,1024,256) fp32
  const float* W = (const float*)d_in[1];   // (3,256,256) fp32
  const float* b = (const float*)d_in[2];   // (256,) fp32
  float* y = (float*)d_out;                 // (8,32,1022,256) fp32
  unsigned short* Wt = (unsigned short*)d_ws;  // 8*3*2*128*32*2 = 393,216 B

  wprep<<<768, 256, 0, stream>>>(W, Wt);
  conv_mfma<<<NIMG * 8 * 2, 256, 0, stream>>>(x, Wt, b, y);
}